// Round 9
// baseline (5110.713 us; speedup 1.0000x reference)
//
#include <hip/hip_runtime.h>

#define DEV __device__ __forceinline__

static constexpr int NB = 64;     // graphs
static constexpr int NN = 1024;   // nodes per graph
static constexpr int NT = NB * NN;

DEV float lrelu(float v){ return v >= 0.f ? v : 0.01f * v; }

// monotone map f32 -> u32 (ascending)
DEV unsigned keyf(float d){
  unsigned u = __float_as_uint(d);
  return (u & 0x80000000u) ? ~u : (u | 0x80000000u);
}

DEV unsigned long long shfl_xor_u64(unsigned long long v, int m){
  unsigned lo = (unsigned)v, hi = (unsigned)(v >> 32);
  lo = (unsigned)__shfl_xor((int)lo, m);
  hi = (unsigned)__shfl_xor((int)hi, m);
  return ((unsigned long long)hi << 32) | (unsigned long long)lo;
}

// ---------------- prep: feat = [tq, x, pos], sq(feat), zero ALL homo counts ------
__global__ __launch_bounds__(256) void prep_kernel(
    const float* __restrict__ x, const float* __restrict__ pos, const float* __restrict__ tq,
    float* __restrict__ feat, float* __restrict__ sqv, unsigned* __restrict__ homoc){
  int n = blockIdx.x * 256 + threadIdx.x;
  if (n < NT){
    float f0 = tq[n], f1 = x[n], f2 = pos[n*3+0], f3 = pos[n*3+1], f4 = pos[n*3+2];
    feat[n*5+0] = f0; feat[n*5+1] = f1; feat[n*5+2] = f2; feat[n*5+3] = f3; feat[n*5+4] = f4;
    sqv[n] = f0*f0 + f1*f1 + f2*f2 + f3*f3 + f4*f4;
  }
  if (blockIdx.x == 0){
    for (int e = threadIdx.x; e < 320; e += 256) homoc[e] = 0u;
  }
}

// ---------------- kNN on 5-dim feat (LDS 24.6KB) ---------------------------------
template<int K, bool EXCL, bool HOMO>
__global__ __launch_bounds__(256) void knn5_kernel(
    const float* __restrict__ feat, const float* __restrict__ sqv,
    int* __restrict__ idx_out, unsigned* __restrict__ homoc){
  __shared__ float fs[NN * 5];
  __shared__ float ss[NN];
  int b = blockIdx.x >> 8;
  int q0 = (blockIdx.x & 255) * 4;
  const float* fg = feat + (size_t)b * NN * 5;
  for (int e = threadIdx.x; e < NN * 5; e += 256) fs[e] = fg[e];
  const float* sg = sqv + (size_t)b * NN;
  for (int e = threadIdx.x; e < NN; e += 256) ss[e] = sg[e];
  __syncthreads();
  int w = threadIdx.x >> 6, lane = threadIdx.x & 63;
  int q = q0 + w;
  float qf[5];
  #pragma unroll
  for (int c = 0; c < 5; ++c) qf[c] = fs[q*5+c];
  float sqq = ss[q];
  unsigned long long keys[16];
  #pragma unroll
  for (int s = 0; s < 16; ++s){
    int c = s * 64 + lane;
    float dot = qf[0]*fs[c*5+0] + qf[1]*fs[c*5+1] + qf[2]*fs[c*5+2] + qf[3]*fs[c*5+3] + qf[4]*fs[c*5+4];
    float d = sqq + ss[c] - 2.f * dot;
    unsigned long long kv = ((unsigned long long)keyf(d) << 32) | (unsigned)c;
    if (EXCL && c == q) kv = ~0ull;
    keys[s] = kv;
  }
  unsigned long long lmin = keys[0];
  #pragma unroll
  for (int s = 1; s < 16; ++s) lmin = keys[s] < lmin ? keys[s] : lmin;
  unsigned cnt[5] = {0,0,0,0,0};
  #pragma unroll 1
  for (int t = 0; t < K; ++t){
    unsigned long long g = lmin;
    #pragma unroll
    for (int d = 1; d < 64; d <<= 1){
      unsigned long long o = shfl_xor_u64(g, d);
      g = o < g ? o : g;
    }
    unsigned c = (unsigned)(g & 0xffffffffull);
    if constexpr (HOMO){
      #pragma unroll
      for (int ch = 0; ch < 5; ++ch) cnt[ch] += (fs[c*5+ch] == qf[ch]) ? 1u : 0u;
    } else {
      if (lane == 0) idx_out[(size_t)(b*NN + q) * K + t] = b*NN + (int)c;
    }
    if (lmin == g){
      unsigned long long nm = ~0ull;
      #pragma unroll
      for (int s = 0; s < 16; ++s){
        if (keys[s] == g) keys[s] = ~0ull;
        nm = keys[s] < nm ? keys[s] : nm;
      }
      lmin = nm;
    }
  }
  if constexpr (HOMO){
    if (lane == 0){
      #pragma unroll
      for (int ch = 0; ch < 5; ++ch) atomicAdd(&homoc[b*5+ch], cnt[ch]);
    }
  }
}

// ---------------- per-node squared norm of 64-dim features -----------------------
__global__ __launch_bounds__(256) void sq64_kernel(const float* __restrict__ X, float* __restrict__ sqv){
  int w = threadIdx.x >> 6, lane = threadIdx.x & 63;
  int node = blockIdx.x * 4 + w;
  float v = X[(size_t)node * 64 + lane];
  float s = v * v;
  #pragma unroll
  for (int d = 1; d < 64; d <<= 1) s += __shfl_xor(s, d);
  if (lane == 0) sqv[node] = s;
}

// ---------------- kNN (k=15) on 64-dim, 128-candidate chunks (LDS 33.5KB) --------
__global__ __launch_bounds__(256) void knn64_kernel(
    const float* __restrict__ X, const float* __restrict__ sqv, int* __restrict__ idx_out){
  __shared__ __align__(16) float chunk[128 * 64];  // swizzled
  __shared__ float sqc[128];
  __shared__ __align__(16) float qf[4][64];
  int b = blockIdx.x >> 8;
  int q0 = (blockIdx.x & 255) * 4;
  int w = threadIdx.x >> 6, lane = threadIdx.x & 63;
  int q = q0 + w;
  int qg = b * NN + q;
  qf[w][lane] = X[(size_t)qg * 64 + lane];
  float sqq = sqv[qg];
  float dist[16];
  #pragma unroll 1
  for (int ch = 0; ch < 8; ++ch){
    __syncthreads();
    {
      const float* xg = X + (size_t)(b * NN + ch * 128) * 64;
      #pragma unroll
      for (int r = 0; r < 8; ++r){
        int e = threadIdx.x + 256 * r;       // e < 2048 : (c, f4)
        int c = e >> 4, f4 = e & 15;
        float4 v = *(const float4*)(xg + c * 64 + f4 * 4);
        *(float4*)&chunk[c * 64 + (((f4 ^ (c & 15))) << 2)] = v;
      }
      if (threadIdx.x < 128) sqc[threadIdx.x] = sqv[b * NN + ch * 128 + threadIdx.x];
    }
    __syncthreads();
    #pragma unroll
    for (int i = 0; i < 2; ++i){
      int cl = lane + 64 * i;
      float acc = 0.f;
      #pragma unroll
      for (int f4 = 0; f4 < 16; ++f4){
        float4 qv = *(const float4*)&qf[w][f4 * 4];
        float4 xv = *(const float4*)&chunk[cl * 64 + (((f4 ^ (cl & 15))) << 2)];
        acc += qv.x*xv.x + qv.y*xv.y + qv.z*xv.z + qv.w*xv.w;
      }
      dist[ch * 2 + i] = sqq + sqc[cl] - 2.f * acc;
    }
  }
  unsigned long long keys[16];
  #pragma unroll
  for (int s = 0; s < 16; ++s){
    int ch = s >> 1, i = s & 1;
    int c = ch * 128 + i * 64 + lane;
    keys[s] = ((unsigned long long)keyf(dist[s]) << 32) | (unsigned)c;
  }
  unsigned long long lmin = keys[0];
  #pragma unroll
  for (int s = 1; s < 16; ++s) lmin = keys[s] < lmin ? keys[s] : lmin;
  #pragma unroll 1
  for (int t = 0; t < 15; ++t){
    unsigned long long g = lmin;
    #pragma unroll
    for (int d = 1; d < 64; d <<= 1){
      unsigned long long o = shfl_xor_u64(g, d);
      g = o < g ? o : g;
    }
    unsigned c = (unsigned)(g & 0xffffffffull);
    if (lane == 0) idx_out[(size_t)qg * 15 + t] = b * NN + (int)c;
    if (lmin == g){
      unsigned long long nm = ~0ull;
      #pragma unroll
      for (int s = 0; s < 16; ++s){
        if (keys[s] == g) keys[s] = ~0ull;
        nm = keys[s] < nm ? keys[s] : nm;
      }
      lmin = nm;
    }
  }
}

// ---------------- per-node U,V with output-column split (LDS <= 33KB) ------------
template<int F, int H1, int YS>
__global__ __launch_bounds__(256) void uv_kernel(
    const float* __restrict__ X, const float* __restrict__ W1, const float* __restrict__ b1,
    float* __restrict__ U, float* __restrict__ V){
  constexpr int HH = H1 / YS;
  __shared__ float w1s[2 * F * HH];
  constexpr int NPI = 256 / HH;
  __shared__ float xs[NPI][F];
  constexpr int NPB = 32;
  int node0 = blockIdx.x * NPB;
  int y0 = blockIdx.y * HH;
  for (int e = threadIdx.x; e < 2 * F * HH; e += 256)
    w1s[e] = W1[(size_t)(e / HH) * H1 + y0 + (e % HH)];
  int ol = threadIdx.x % HH, nn = threadIdx.x / HH;
  float b1o = b1[y0 + ol];
  for (int it = 0; it < NPB / NPI; ++it){
    __syncthreads();
    int nbase = node0 + it * NPI;
    for (int e = threadIdx.x; e < NPI * F; e += 256)
      xs[e / F][e % F] = X[(size_t)(nbase + e / F) * F + (e % F)];
    __syncthreads();
    float u = b1o, v = 0.f;
    #pragma unroll
    for (int f = 0; f < F; ++f){
      float xf = xs[nn][f];
      float wt = w1s[f * HH + ol], wb = w1s[(F + f) * HH + ol];
      u += xf * (wt - wb);
      v += xf * wb;
    }
    size_t node = nbase + nn;
    U[node * H1 + y0 + ol] = u;
    V[node * H1 + y0 + ol] = v;
  }
}

// ---------------- edge aggregation (LDS <= 63.7KB) -------------------------------
template<int H1>
__global__ __launch_bounds__(256) void edge_kernel(
    const float* __restrict__ U, const float* __restrict__ V,
    const int* __restrict__ idx15, const float* __restrict__ W2,
    const float* __restrict__ b2, float* __restrict__ out, int base){
  constexpr int H14 = H1 / 4;
  __shared__ __align__(16) float w2t[64 * H1];        // [o][h] xor-swizzled
  __shared__ __align__(16) float h1s[4][15 * H1];
  __shared__ int idxs[4][16];
  int w = threadIdx.x >> 6, lane = threadIdx.x & 63;
  int node_l = blockIdx.x * 4 + w;
  int node_g = base + node_l;
  for (int e = threadIdx.x; e < 64 * H14; e += 256){
    int o = e & 63, h4 = e >> 6;
    float vv[4];
    #pragma unroll
    for (int j = 0; j < 4; ++j) vv[j] = W2[(size_t)(h4 * 4 + j) * 64 + o];
    float* dst = &w2t[o * H1 + (((h4 ^ (o & 7))) << 2)];
    #pragma unroll
    for (int j = 0; j < 4; ++j) dst[j] = vv[j];
  }
  if (lane < 15) idxs[w][lane] = idx15[(size_t)node_g * 15 + lane] - base;
  __syncthreads();
  for (int e = lane; e < 15 * H14; e += 64){
    int j = e / H14, h4 = e % H14;
    int jn = idxs[w][j];
    float4 uu = *(const float4*)(U + (size_t)node_l * H1 + h4 * 4);
    float4 vv = *(const float4*)(V + (size_t)jn * H1 + h4 * 4);
    float4 h;
    h.x = lrelu(uu.x + vv.x); h.y = lrelu(uu.y + vv.y);
    h.z = lrelu(uu.z + vv.z); h.w = lrelu(uu.w + vv.w);
    *(float4*)&h1s[w][j * H1 + h4 * 4] = h;
  }
  __syncthreads();
  int o = lane;
  float acc[15];
  #pragma unroll
  for (int j = 0; j < 15; ++j) acc[j] = 0.f;
  for (int h4 = 0; h4 < H14; ++h4){
    float4 wv = *(const float4*)&w2t[o * H1 + (((h4 ^ (o & 7))) << 2)];
    #pragma unroll
    for (int j = 0; j < 15; ++j){
      float4 hv = *(const float4*)&h1s[w][j * H1 + h4 * 4];
      acc[j] += wv.x*hv.x + wv.y*hv.y + wv.z*hv.z + wv.w*hv.w;
    }
  }
  float b2o = b2[o];
  float s = 0.f;
  #pragma unroll
  for (int j = 0; j < 15; ++j) s += lrelu(acc[j] + b2o);
  out[(size_t)node_g * 64 + o] = s;
}

// ---------------- GEMM1: h = lrelu(cat @ l1_W1 + b1) -> fp32 chunk-local ---------
__global__ __launch_bounds__(256) void gemm1_kernel(
    const float* __restrict__ feat, const float* __restrict__ x1,
    const float* __restrict__ x2, const float* __restrict__ x3,
    const float* __restrict__ W1, const float* __restrict__ b1,
    float* __restrict__ hbuf, int base){
  __shared__ __align__(16) float As[16][64];
  __shared__ __align__(16) float Bs[16][64];
  int node0 = blockIdx.x * 64, n0 = blockIdx.y * 64;
  int tid = threadIdx.x, tx = tid & 15, ty = tid >> 4;
  float acc[4][4] = {};
  for (int k0 = 0; k0 < 197; k0 += 16){
    __syncthreads();
    #pragma unroll
    for (int r = 0; r < 4; ++r){
      int e = tid + 256 * r;
      int k = e >> 6, m = e & 63;
      int kk = k0 + k;
      size_t node = (size_t)base + node0 + m;
      float v;
      if (kk < 5) v = feat[node * 5 + kk];
      else if (kk < 69)  v = x1[node * 64 + kk - 5];
      else if (kk < 133) v = x2[node * 64 + kk - 69];
      else if (kk < 197) v = x3[node * 64 + kk - 133];
      else v = 0.f;
      As[k][m] = v;
      Bs[k][m] = (kk < 197) ? W1[(size_t)kk * 512 + n0 + m] : 0.f;
    }
    __syncthreads();
    #pragma unroll
    for (int k = 0; k < 16; ++k){
      float4 a = *(const float4*)&As[k][ty * 4];
      float4 bq = *(const float4*)&Bs[k][tx * 4];
      acc[0][0]+=a.x*bq.x; acc[0][1]+=a.x*bq.y; acc[0][2]+=a.x*bq.z; acc[0][3]+=a.x*bq.w;
      acc[1][0]+=a.y*bq.x; acc[1][1]+=a.y*bq.y; acc[1][2]+=a.y*bq.z; acc[1][3]+=a.y*bq.w;
      acc[2][0]+=a.z*bq.x; acc[2][1]+=a.z*bq.y; acc[2][2]+=a.z*bq.z; acc[2][3]+=a.z*bq.w;
      acc[3][0]+=a.w*bq.x; acc[3][1]+=a.w*bq.y; acc[3][2]+=a.w*bq.z; acc[3][3]+=a.w*bq.w;
    }
  }
  #pragma unroll
  for (int i = 0; i < 4; ++i){
    size_t node = node0 + ty * 4 + i;
    float4 st;
    st.x = lrelu(acc[i][0] + b1[n0 + tx*4 + 0]);
    st.y = lrelu(acc[i][1] + b1[n0 + tx*4 + 1]);
    st.z = lrelu(acc[i][2] + b1[n0 + tx*4 + 2]);
    st.w = lrelu(acc[i][3] + b1[n0 + tx*4 + 3]);
    *(float4*)(hbuf + node * 512 + n0 + tx * 4) = st;
  }
}

// ---------------- GEMM2: out = h @ l1_W2 + b2, fused per-graph partial col-sum ---
__global__ __launch_bounds__(256) void gemm2_kernel(
    const float* __restrict__ hbuf, const float* __restrict__ W2,
    const float* __restrict__ b2, float* __restrict__ parts, int base){
  __shared__ __align__(16) float As[16][64];
  __shared__ __align__(16) float Bs[16][64];
  __shared__ float red[16][64];
  int node0 = blockIdx.x * 64, n0 = blockIdx.y * 64;
  int tid = threadIdx.x, tx = tid & 15, ty = tid >> 4;
  float acc[4][4] = {};
  for (int k0 = 0; k0 < 512; k0 += 16){
    __syncthreads();
    {
      int m = tid >> 2, k4 = (tid & 3) * 4;
      float4 hv = *(const float4*)(hbuf + (size_t)(node0 + m) * 512 + k0 + k4);
      As[k4 + 0][m] = hv.x;
      As[k4 + 1][m] = hv.y;
      As[k4 + 2][m] = hv.z;
      As[k4 + 3][m] = hv.w;
      #pragma unroll
      for (int r = 0; r < 4; ++r){
        int e = tid + 256 * r;
        int k = e >> 6, n = e & 63;
        Bs[k][n] = W2[(size_t)(k0 + k) * 256 + n0 + n];
      }
    }
    __syncthreads();
    #pragma unroll
    for (int k = 0; k < 16; ++k){
      float4 a = *(const float4*)&As[k][ty * 4];
      float4 bq = *(const float4*)&Bs[k][tx * 4];
      acc[0][0]+=a.x*bq.x; acc[0][1]+=a.x*bq.y; acc[0][2]+=a.x*bq.z; acc[0][3]+=a.x*bq.w;
      acc[1][0]+=a.y*bq.x; acc[1][1]+=a.y*bq.y; acc[1][2]+=a.y*bq.z; acc[1][3]+=a.y*bq.w;
      acc[2][0]+=a.z*bq.x; acc[2][1]+=a.z*bq.y; acc[2][2]+=a.z*bq.z; acc[2][3]+=a.z*bq.w;
      acc[3][0]+=a.w*bq.x; acc[3][1]+=a.w*bq.y; acc[3][2]+=a.w*bq.z; acc[3][3]+=a.w*bq.w;
    }
  }
  float cs[4];
  #pragma unroll
  for (int c = 0; c < 4; ++c){
    float bb = b2[n0 + tx * 4 + c];
    cs[c] = (acc[0][c] + bb) + (acc[1][c] + bb) + (acc[2][c] + bb) + (acc[3][c] + bb);
  }
  __syncthreads();
  red[ty][tx*4+0] = cs[0]; red[ty][tx*4+1] = cs[1];
  red[ty][tx*4+2] = cs[2]; red[ty][tx*4+3] = cs[3];
  __syncthreads();
  if (tid < 64){
    float s = 0.f;
    #pragma unroll
    for (int t = 0; t < 16; ++t) s += red[t][tid];
    int node_g0 = base + node0;
    int g = node_g0 >> 10;
    int blk = (node_g0 >> 6) & 15;
    parts[(size_t)(g * 16 + blk) * 256 + n0 + tid] = s;
  }
}

// ---------------- final: per-graph mean, homophily, head MLP; OUT IS FLOAT32 -----
__global__ __launch_bounds__(256) void final_kernel(
    const float* __restrict__ parts, const unsigned* __restrict__ homoc,
    const float* __restrict__ mW1, const float* __restrict__ mb1,
    const float* __restrict__ mW2, const float* __restrict__ mb2,
    float* __restrict__ out){
  __shared__ float gv[261];
  __shared__ float z[256];
  int g = blockIdx.x, t = threadIdx.x;
  float s = 0.f;
  #pragma unroll
  for (int p = 0; p < 16; ++p) s += parts[(size_t)(g * 16 + p) * 256 + t];
  float dmean = s * (1.f / 1024.f);
  gv[t] = lrelu(dmean);
  if (t < 5) gv[256 + t] = lrelu((float)homoc[g * 5 + t] * (1.f / 97280.f));
  __syncthreads();
  float acc = mb1[t];
  for (int f = 0; f < 261; ++f) acc += gv[f] * mW1[(size_t)f * 256 + t];
  z[t] = lrelu(acc);
  __syncthreads();
  if (t < 3){
    float o = mb2[t];
    for (int f = 0; f < 256; ++f) o += z[f] * mW2[f * 3 + t];
    out[g * 3 + t] = o;
  }
}

// ---------------- diag: encode HARD failure info into out[0] ---------------------
__global__ __launch_bounds__(64) void diag_kernel(float* out, float hostcode){
  if (threadIdx.x == 0 && hostcode != 0.f) out[0] = hostcode;
}

extern "C" void kernel_launch(void* const* d_in, const int* in_sizes, int n_in,
                              void* d_out, int out_size, void* d_ws, size_t ws_size,
                              hipStream_t stream){
  (void)out_size;
  // ---- input mapping verified against in_sizes (identity / batch-drop / batch-tail)
  static const int E[20] = {65536,196608,65536,65536,640,64,4096,64,16384,128,8192,64,
                            100864,512,131072,256,66816,256,768,3};
  int map[20];
  float hostcode = 0.f;
  bool runnable = true;
  for (int i = 0; i < 20; ++i) map[i] = (i < n_in) ? i : 0;
  if (n_in < 19){
    hostcode = 4.0e7f; runnable = false;
  } else {
    bool ident = (n_in >= 20);
    if (ident) for (int i = 0; i < 20; ++i) if (in_sizes[i] != E[i]) { ident = false; break; }
    if (!ident){
      bool drop = true;
      for (int i = 0; i < 19 && drop; ++i){
        int ei = (i < 3) ? i : i + 1;
        if (in_sizes[i] != E[ei]) drop = false;
      }
      bool tail = false;
      if (!drop && n_in >= 20){
        tail = true;
        for (int i = 0; i < 19 && tail; ++i){
          int ei = (i < 3) ? i : i + 1;
          if (in_sizes[i] != E[ei]) tail = false;
        }
        if (tail && in_sizes[19] != E[3]) tail = false;
      }
      if (drop){
        for (int i = 0; i < 3; ++i) map[i] = i;
        map[3] = 0;
        for (int i = 4; i < 20; ++i) map[i] = i - 1;
      } else if (tail){
        for (int i = 0; i < 3; ++i) map[i] = i;
        map[3] = 19;
        for (int i = 4; i < 20; ++i) map[i] = i - 1;
      } else {
        int firstbad = 0;
        for (int i = 0; i < 20; ++i){
          if (i >= n_in || in_sizes[i] != E[i]) { firstbad = i; break; }
        }
        hostcode = 2.0e7f + 1.0e6f * (float)firstbad;
      }
    }
  }
  const float* x    = (const float*)d_in[map[0]];
  const float* pos  = (const float*)d_in[map[1]];
  const float* tq   = (const float*)d_in[map[2]];
  const float* c1W1 = (const float*)d_in[map[4]];
  const float* c1b1 = (const float*)d_in[map[5]];
  const float* c1W2 = (const float*)d_in[map[6]];
  const float* c1b2 = (const float*)d_in[map[7]];
  const float* c2W1 = (const float*)d_in[map[8]];
  const float* c2b1 = (const float*)d_in[map[9]];
  const float* c2W2 = (const float*)d_in[map[10]];
  const float* c2b2 = (const float*)d_in[map[11]];
  const float* l1W1 = (const float*)d_in[map[12]];
  const float* l1b1 = (const float*)d_in[map[13]];
  const float* l1W2 = (const float*)d_in[map[14]];
  const float* l1b2 = (const float*)d_in[map[15]];
  const float* mW1  = (const float*)d_in[map[16]];
  const float* mb1  = (const float*)d_in[map[17]];
  const float* mW2  = (const float*)d_in[map[18]];
  const float* mb2  = (const float*)d_in[map[19]];

  char* wsb = (char*)d_ws;
  size_t off = 0;
  auto alloc = [&](size_t bytes) -> char* {
    char* p = wsb + off;
    off += (bytes + 255) & ~(size_t)255;
    return p;
  };
  float* feat  = (float*)alloc((size_t)NT * 5 * 4);
  float* sqv   = (float*)alloc((size_t)NT * 4);
  float* xf1   = (float*)alloc((size_t)NT * 64 * 4);
  float* xf2   = (float*)alloc((size_t)NT * 64 * 4);
  float* xf3   = (float*)alloc((size_t)NT * 64 * 4);
  int*   idx15 = (int*)alloc((size_t)NT * 15 * 4);
  unsigned* homoc = (unsigned*)alloc(320 * 4);
  float* parts = (float*)alloc((size_t)NB * 16 * 256 * 4);

  size_t fixed_off = off;
  int C = 4;
  while (C < 64 && fixed_off + (size_t)(NT / C) * 2048 + 256 > ws_size) C <<= 1;
  int chunkN = NT / C;
  bool wsbad = fixed_off + (size_t)chunkN * 2048 + 256 > ws_size;
  float* R    = (float*)alloc((size_t)chunkN * 2048);
  float* U    = R;
  float* V64  = R + (size_t)chunkN * 64;
  float* V128 = R + (size_t)chunkN * 128;
  float* hbuf = R;
  if (wsbad && hostcode == 0.f) hostcode = 5.0e6f;

  int ftype = 0;
  (void)hipGetLastError();
  #define LCK(ty) do { if (hipGetLastError() != hipSuccess && ftype == 0) ftype = (ty); } while(0)

  dim3 blk(256);
  if (runnable){
    prep_kernel<<<dim3((NT + 255) / 256), blk, 0, stream>>>(x, pos, tq, feat, sqv, homoc);
    LCK(1);
    knn5_kernel<95, true, true><<<dim3(NB * 256), blk, 0, stream>>>(feat, sqv, nullptr, homoc);
    LCK(2);
    knn5_kernel<15, false, false><<<dim3(NB * 256), blk, 0, stream>>>(feat, sqv, idx15, nullptr);
    LCK(3);

    if (!wsbad){
      for (int c = 0; c < C; ++c){
        int base = c * chunkN;
        uv_kernel<5, 64, 1><<<dim3(chunkN / 32, 1), blk, 0, stream>>>(feat + (size_t)base * 5, c1W1, c1b1, U, V64);
        LCK(4);
        edge_kernel<64><<<dim3(chunkN / 4), blk, 0, stream>>>(U, V64, idx15, c1W2, c1b2, xf1, base);
        LCK(5);
      }
      sq64_kernel<<<dim3(NT / 4), blk, 0, stream>>>(xf1, sqv);
      LCK(6);
      knn64_kernel<<<dim3(NB * 256), blk, 0, stream>>>(xf1, sqv, idx15);
      LCK(7);
      for (int c = 0; c < C; ++c){
        int base = c * chunkN;
        uv_kernel<64, 128, 2><<<dim3(chunkN / 32, 2), blk, 0, stream>>>(xf1 + (size_t)base * 64, c2W1, c2b1, U, V128);
        LCK(8);
        edge_kernel<128><<<dim3(chunkN / 4), blk, 0, stream>>>(U, V128, idx15, c2W2, c2b2, xf2, base);
        LCK(9);
      }
      sq64_kernel<<<dim3(NT / 4), blk, 0, stream>>>(xf2, sqv);
      LCK(6);
      knn64_kernel<<<dim3(NB * 256), blk, 0, stream>>>(xf2, sqv, idx15);
      LCK(7);
      for (int c = 0; c < C; ++c){
        int base = c * chunkN;
        uv_kernel<64, 128, 2><<<dim3(chunkN / 32, 2), blk, 0, stream>>>(xf2 + (size_t)base * 64, c2W1, c2b1, U, V128);
        LCK(8);
        edge_kernel<128><<<dim3(chunkN / 4), blk, 0, stream>>>(U, V128, idx15, c2W2, c2b2, xf3, base);
        LCK(9);
      }
      for (int c = 0; c < C; ++c){
        int base = c * chunkN;
        gemm1_kernel<<<dim3(chunkN / 64, 8), blk, 0, stream>>>(feat, xf1, xf2, xf3, l1W1, l1b1, hbuf, base);
        LCK(10);
        gemm2_kernel<<<dim3(chunkN / 64, 4), blk, 0, stream>>>(hbuf, l1W2, l1b2, parts, base);
        LCK(11);
      }
    }
    final_kernel<<<dim3(NB), blk, 0, stream>>>(parts, homoc, mW1, mb1, mW2, mb2, (float*)d_out);
    LCK(12);
  }
  if (ftype != 0 && hostcode == 0.f) hostcode = 1.0e7f * (float)ftype;
  diag_kernel<<<dim3(1), dim3(64), 0, stream>>>((float*)d_out, hostcode);
  #undef LCK
}

// Round 10
// 4288.248 us; speedup vs baseline: 1.1918x; 1.1918x over previous
//
#include <hip/hip_runtime.h>

#define DEV __device__ __forceinline__

static constexpr int NB = 64;     // graphs
static constexpr int NN = 1024;   // nodes per graph
static constexpr int NT = NB * NN;

DEV float lrelu(float v){ return v >= 0.f ? v : 0.01f * v; }

// monotone map f32 -> u32 (ascending)
DEV unsigned keyf(float d){
  unsigned u = __float_as_uint(d);
  return (u & 0x80000000u) ? ~u : (u | 0x80000000u);
}

DEV void wave_lds_fence(){
  __builtin_amdgcn_wave_barrier();
  asm volatile("s_waitcnt lgkmcnt(0)" ::: "memory");
  __builtin_amdgcn_sched_barrier(0);
  __builtin_amdgcn_wave_barrier();
}

// Exact k-th-smallest selection over the wave's 1024 unique u64 keys (16/lane).
// On return: key selected iff (key >> shift_out) <= prefix_out (exactly k keys).
// hist = per-wave 256-entry LDS scratch. Wave-level sync only.
DEV void radix_kth(const unsigned long long* keys, int k, unsigned* hist,
                   unsigned long long& prefix_out, int& shift_out){
  int lane = threadIdx.x & 63;
  unsigned long long prefix = 0;
  unsigned kk = (unsigned)k;
  #pragma unroll 1
  for (int p = 0; p < 8; ++p){
    int shift = 56 - 8 * p;
    #pragma unroll
    for (int i = 0; i < 4; ++i) hist[lane * 4 + i] = 0u;
    wave_lds_fence();
    #pragma unroll
    for (int s = 0; s < 16; ++s){
      unsigned long long key = keys[s];
      bool match = (p == 0) || ((key >> (shift + 8)) == prefix);
      if (match) atomicAdd(&hist[(unsigned)(key >> shift) & 255u], 1u);
    }
    wave_lds_fence();
    unsigned c0 = hist[lane*4+0], c1 = hist[lane*4+1], c2 = hist[lane*4+2], c3 = hist[lane*4+3];
    unsigned s4 = c0 + c1 + c2 + c3;
    unsigned incl = s4;
    #pragma unroll
    for (int d = 1; d < 64; d <<= 1){
      unsigned t = (unsigned)__shfl_up((int)incl, d);
      if (lane >= d) incl += t;
    }
    unsigned excl = incl - s4;
    bool flag = (excl < kk) && (kk <= excl + s4);
    int bstar = 0; unsigned less = 0, cnt = 0;
    if (flag){
      unsigned cs[4] = {c0, c1, c2, c3};
      unsigned cum = excl;
      #pragma unroll
      for (int i = 0; i < 4; ++i){
        if (cnt == 0u && kk > cum && kk <= cum + cs[i]){
          bstar = lane * 4 + i; less = cum; cnt = cs[i];
        }
        cum += cs[i];
      }
    }
    unsigned long long bm = __ballot(flag);
    int src = __ffsll((long long)bm) - 1;
    bstar = __shfl(bstar, src);
    less  = (unsigned)__shfl((int)less, src);
    cnt   = (unsigned)__shfl((int)cnt, src);
    prefix = (prefix << 8) | (unsigned long long)(unsigned)bstar;
    kk -= less;
    if (kk == cnt){ prefix_out = prefix; shift_out = shift; return; }
  }
  prefix_out = prefix; shift_out = 0;
}

// ---------------- prep: feat = [tq, x, pos], sq(feat), zero ALL homo counts ------
__global__ __launch_bounds__(256) void prep_kernel(
    const float* __restrict__ x, const float* __restrict__ pos, const float* __restrict__ tq,
    float* __restrict__ feat, float* __restrict__ sqv, unsigned* __restrict__ homoc){
  int n = blockIdx.x * 256 + threadIdx.x;
  if (n < NT){
    float f0 = tq[n], f1 = x[n], f2 = pos[n*3+0], f3 = pos[n*3+1], f4 = pos[n*3+2];
    feat[n*5+0] = f0; feat[n*5+1] = f1; feat[n*5+2] = f2; feat[n*5+3] = f3; feat[n*5+4] = f4;
    sqv[n] = f0*f0 + f1*f1 + f2*f2 + f3*f3 + f4*f4;
  }
  if (blockIdx.x == 0){
    for (int e = threadIdx.x; e < 320; e += 256) homoc[e] = 0u;
  }
}

// ---------------- fused kNN on 5-dim feat: K=15 idx write + K=95 homophily -------
__global__ __launch_bounds__(256) void knn5f_kernel(
    const float* __restrict__ feat, const float* __restrict__ sqv,
    int* __restrict__ idx_out, unsigned* __restrict__ homoc){
  __shared__ float fs[NN * 5];
  __shared__ float ss[NN];
  __shared__ unsigned hist[4][256];
  __shared__ unsigned wctr[4];
  int b = blockIdx.x >> 8;
  int q0 = (blockIdx.x & 255) * 4;
  const float* fg = feat + (size_t)b * NN * 5;
  for (int e = threadIdx.x; e < NN * 5; e += 256) fs[e] = fg[e];
  const float* sg = sqv + (size_t)b * NN;
  for (int e = threadIdx.x; e < NN; e += 256) ss[e] = sg[e];
  __syncthreads();
  int w = threadIdx.x >> 6, lane = threadIdx.x & 63;
  int q = q0 + w;
  float qf[5];
  #pragma unroll
  for (int c = 0; c < 5; ++c) qf[c] = fs[q*5+c];
  float sqq = ss[q];
  unsigned long long keys[16];
  #pragma unroll
  for (int s = 0; s < 16; ++s){
    int c = s * 64 + lane;
    float dot = qf[0]*fs[c*5+0] + qf[1]*fs[c*5+1] + qf[2]*fs[c*5+2] + qf[3]*fs[c*5+3] + qf[4]*fs[c*5+4];
    float d = sqq + ss[c] - 2.f * dot;
    keys[s] = ((unsigned long long)keyf(d) << 32) | (unsigned)c;
  }
  // --- selection 1: K=15, self included (self dist = 0 exactly -> always in) ----
  unsigned long long pfx; int sh;
  radix_kth(keys, 15, &hist[w][0], pfx, sh);
  if (lane == 0) wctr[w] = 0u;
  wave_lds_fence();
  #pragma unroll
  for (int s = 0; s < 16; ++s){
    unsigned long long key = keys[s];
    if ((key >> sh) <= pfx){
      unsigned pos = atomicAdd(&wctr[w], 1u);
      idx_out[(size_t)(b*NN + q) * 15 + pos] = b*NN + (int)(key & 0xffffffffull);
    }
  }
  // --- selection 2: K=95, self excluded; count homophily -----------------------
  #pragma unroll
  for (int s = 0; s < 16; ++s)
    if ((unsigned)(keys[s] & 0xffffffffull) == (unsigned)q) keys[s] = ~0ull;
  radix_kth(keys, 95, &hist[w][0], pfx, sh);
  unsigned cnt5[5] = {0,0,0,0,0};
  #pragma unroll
  for (int s = 0; s < 16; ++s){
    unsigned long long key = keys[s];
    if ((key >> sh) <= pfx){
      int c = (int)(key & 0xffffffffull);
      #pragma unroll
      for (int ch = 0; ch < 5; ++ch) cnt5[ch] += (fs[c*5+ch] == qf[ch]) ? 1u : 0u;
    }
  }
  #pragma unroll
  for (int ch = 0; ch < 5; ++ch){
    unsigned v = cnt5[ch];
    #pragma unroll
    for (int d = 32; d >= 1; d >>= 1) v += (unsigned)__shfl_xor((int)v, d);
    if (lane == 0) atomicAdd(&homoc[b*5+ch], v);
  }
}

// ---------------- kNN (k=15) on 64-dim, 128-candidate chunks + radix select ------
__global__ __launch_bounds__(256) void knn64_kernel(
    const float* __restrict__ X, const float* __restrict__ sqv, int* __restrict__ idx_out){
  __shared__ __align__(16) float chunk[128 * 64];  // swizzled
  __shared__ float sqc[128];
  __shared__ __align__(16) float qf[4][64];
  __shared__ unsigned hist[4][256];
  __shared__ unsigned wctr[4];
  int b = blockIdx.x >> 8;
  int q0 = (blockIdx.x & 255) * 4;
  int w = threadIdx.x >> 6, lane = threadIdx.x & 63;
  int q = q0 + w;
  int qg = b * NN + q;
  qf[w][lane] = X[(size_t)qg * 64 + lane];
  float sqq = sqv[qg];
  float dist[16];
  #pragma unroll 1
  for (int ch = 0; ch < 8; ++ch){
    __syncthreads();
    {
      const float* xg = X + (size_t)(b * NN + ch * 128) * 64;
      #pragma unroll
      for (int r = 0; r < 8; ++r){
        int e = threadIdx.x + 256 * r;       // e < 2048 : (c, f4)
        int c = e >> 4, f4 = e & 15;
        float4 v = *(const float4*)(xg + c * 64 + f4 * 4);
        *(float4*)&chunk[c * 64 + (((f4 ^ (c & 15))) << 2)] = v;
      }
      if (threadIdx.x < 128) sqc[threadIdx.x] = sqv[b * NN + ch * 128 + threadIdx.x];
    }
    __syncthreads();
    #pragma unroll
    for (int i = 0; i < 2; ++i){
      int cl = lane + 64 * i;
      float acc = 0.f;
      #pragma unroll
      for (int f4 = 0; f4 < 16; ++f4){
        float4 qv = *(const float4*)&qf[w][f4 * 4];
        float4 xv = *(const float4*)&chunk[cl * 64 + (((f4 ^ (cl & 15))) << 2)];
        acc += qv.x*xv.x + qv.y*xv.y + qv.z*xv.z + qv.w*xv.w;
      }
      dist[ch * 2 + i] = sqq + sqc[cl] - 2.f * acc;
    }
  }
  unsigned long long keys[16];
  #pragma unroll
  for (int s = 0; s < 16; ++s){
    int ch = s >> 1, i = s & 1;
    int c = ch * 128 + i * 64 + lane;
    keys[s] = ((unsigned long long)keyf(dist[s]) << 32) | (unsigned)c;
  }
  unsigned long long pfx; int sh;
  radix_kth(keys, 15, &hist[w][0], pfx, sh);
  if (lane == 0) wctr[w] = 0u;
  wave_lds_fence();
  #pragma unroll
  for (int s = 0; s < 16; ++s){
    unsigned long long key = keys[s];
    if ((key >> sh) <= pfx){
      unsigned pos = atomicAdd(&wctr[w], 1u);
      idx_out[(size_t)qg * 15 + pos] = b * NN + (int)(key & 0xffffffffull);
    }
  }
}

// ---------------- per-node U,V with output-column split (LDS <= 33KB) ------------
template<int F, int H1, int YS>
__global__ __launch_bounds__(256) void uv_kernel(
    const float* __restrict__ X, const float* __restrict__ W1, const float* __restrict__ b1,
    float* __restrict__ U, float* __restrict__ V){
  constexpr int HH = H1 / YS;
  __shared__ float w1s[2 * F * HH];
  constexpr int NPI = 256 / HH;
  __shared__ float xs[NPI][F];
  constexpr int NPB = 32;
  int node0 = blockIdx.x * NPB;
  int y0 = blockIdx.y * HH;
  for (int e = threadIdx.x; e < 2 * F * HH; e += 256)
    w1s[e] = W1[(size_t)(e / HH) * H1 + y0 + (e % HH)];
  int ol = threadIdx.x % HH, nn = threadIdx.x / HH;
  float b1o = b1[y0 + ol];
  for (int it = 0; it < NPB / NPI; ++it){
    __syncthreads();
    int nbase = node0 + it * NPI;
    for (int e = threadIdx.x; e < NPI * F; e += 256)
      xs[e / F][e % F] = X[(size_t)(nbase + e / F) * F + (e % F)];
    __syncthreads();
    float u = b1o, v = 0.f;
    #pragma unroll
    for (int f = 0; f < F; ++f){
      float xf = xs[nn][f];
      float wt = w1s[f * HH + ol], wb = w1s[(F + f) * HH + ol];
      u += xf * (wt - wb);
      v += xf * wb;
    }
    size_t node = nbase + nn;
    U[node * H1 + y0 + ol] = u;
    V[node * H1 + y0 + ol] = v;
  }
}

// ---------------- edge aggregation; optional fused sq-norm write -----------------
template<int H1, bool WRSQ>
__global__ __launch_bounds__(256) void edge_kernel(
    const float* __restrict__ U, const float* __restrict__ V,
    const int* __restrict__ idx15, const float* __restrict__ W2,
    const float* __restrict__ b2, float* __restrict__ out,
    float* __restrict__ sqv, int base){
  constexpr int H14 = H1 / 4;
  __shared__ __align__(16) float w2t[64 * H1];        // [o][h] xor-swizzled
  __shared__ __align__(16) float h1s[4][15 * H1];
  __shared__ int idxs[4][16];
  int w = threadIdx.x >> 6, lane = threadIdx.x & 63;
  int node_l = blockIdx.x * 4 + w;
  int node_g = base + node_l;
  for (int e = threadIdx.x; e < 64 * H14; e += 256){
    int o = e & 63, h4 = e >> 6;
    float vv[4];
    #pragma unroll
    for (int j = 0; j < 4; ++j) vv[j] = W2[(size_t)(h4 * 4 + j) * 64 + o];
    float* dst = &w2t[o * H1 + (((h4 ^ (o & 7))) << 2)];
    #pragma unroll
    for (int j = 0; j < 4; ++j) dst[j] = vv[j];
  }
  if (lane < 15) idxs[w][lane] = idx15[(size_t)node_g * 15 + lane] - base;
  __syncthreads();
  for (int e = lane; e < 15 * H14; e += 64){
    int j = e / H14, h4 = e % H14;
    int jn = idxs[w][j];
    float4 uu = *(const float4*)(U + (size_t)node_l * H1 + h4 * 4);
    float4 vv = *(const float4*)(V + (size_t)jn * H1 + h4 * 4);
    float4 h;
    h.x = lrelu(uu.x + vv.x); h.y = lrelu(uu.y + vv.y);
    h.z = lrelu(uu.z + vv.z); h.w = lrelu(uu.w + vv.w);
    *(float4*)&h1s[w][j * H1 + h4 * 4] = h;
  }
  __syncthreads();
  int o = lane;
  float acc[15];
  #pragma unroll
  for (int j = 0; j < 15; ++j) acc[j] = 0.f;
  for (int h4 = 0; h4 < H14; ++h4){
    float4 wv = *(const float4*)&w2t[o * H1 + (((h4 ^ (o & 7))) << 2)];
    #pragma unroll
    for (int j = 0; j < 15; ++j){
      float4 hv = *(const float4*)&h1s[w][j * H1 + h4 * 4];
      acc[j] += wv.x*hv.x + wv.y*hv.y + wv.z*hv.z + wv.w*hv.w;
    }
  }
  float b2o = b2[o];
  float s = 0.f;
  #pragma unroll
  for (int j = 0; j < 15; ++j) s += lrelu(acc[j] + b2o);
  out[(size_t)node_g * 64 + o] = s;
  if (WRSQ){
    float s2 = s * s;
    #pragma unroll
    for (int d = 1; d < 64; d <<= 1) s2 += __shfl_xor(s2, d);
    if (lane == 0) sqv[node_g] = s2;
  }
}

// ---------------- GEMM1: h = lrelu(cat @ l1_W1 + b1) -> fp32 chunk-local ---------
__global__ __launch_bounds__(256) void gemm1_kernel(
    const float* __restrict__ feat, const float* __restrict__ x1,
    const float* __restrict__ x2, const float* __restrict__ x3,
    const float* __restrict__ W1, const float* __restrict__ b1,
    float* __restrict__ hbuf, int base){
  __shared__ __align__(16) float As[16][64];
  __shared__ __align__(16) float Bs[16][64];
  int node0 = blockIdx.x * 64, n0 = blockIdx.y * 64;
  int tid = threadIdx.x, tx = tid & 15, ty = tid >> 4;
  float acc[4][4] = {};
  for (int k0 = 0; k0 < 197; k0 += 16){
    __syncthreads();
    #pragma unroll
    for (int r = 0; r < 4; ++r){
      int e = tid + 256 * r;
      int k = e >> 6, m = e & 63;
      int kk = k0 + k;
      size_t node = (size_t)base + node0 + m;
      float v;
      if (kk < 5) v = feat[node * 5 + kk];
      else if (kk < 69)  v = x1[node * 64 + kk - 5];
      else if (kk < 133) v = x2[node * 64 + kk - 69];
      else if (kk < 197) v = x3[node * 64 + kk - 133];
      else v = 0.f;
      As[k][m] = v;
      Bs[k][m] = (kk < 197) ? W1[(size_t)kk * 512 + n0 + m] : 0.f;
    }
    __syncthreads();
    #pragma unroll
    for (int k = 0; k < 16; ++k){
      float4 a = *(const float4*)&As[k][ty * 4];
      float4 bq = *(const float4*)&Bs[k][tx * 4];
      acc[0][0]+=a.x*bq.x; acc[0][1]+=a.x*bq.y; acc[0][2]+=a.x*bq.z; acc[0][3]+=a.x*bq.w;
      acc[1][0]+=a.y*bq.x; acc[1][1]+=a.y*bq.y; acc[1][2]+=a.y*bq.z; acc[1][3]+=a.y*bq.w;
      acc[2][0]+=a.z*bq.x; acc[2][1]+=a.z*bq.y; acc[2][2]+=a.z*bq.z; acc[2][3]+=a.z*bq.w;
      acc[3][0]+=a.w*bq.x; acc[3][1]+=a.w*bq.y; acc[3][2]+=a.w*bq.z; acc[3][3]+=a.w*bq.w;
    }
  }
  #pragma unroll
  for (int i = 0; i < 4; ++i){
    size_t node = node0 + ty * 4 + i;
    float4 st;
    st.x = lrelu(acc[i][0] + b1[n0 + tx*4 + 0]);
    st.y = lrelu(acc[i][1] + b1[n0 + tx*4 + 1]);
    st.z = lrelu(acc[i][2] + b1[n0 + tx*4 + 2]);
    st.w = lrelu(acc[i][3] + b1[n0 + tx*4 + 3]);
    *(float4*)(hbuf + node * 512 + n0 + tx * 4) = st;
  }
}

// ---------------- GEMM2: out = h @ l1_W2 + b2, fused per-graph partial col-sum ---
__global__ __launch_bounds__(256) void gemm2_kernel(
    const float* __restrict__ hbuf, const float* __restrict__ W2,
    const float* __restrict__ b2, float* __restrict__ parts, int base){
  __shared__ __align__(16) float As[16][64];
  __shared__ __align__(16) float Bs[16][64];
  __shared__ float red[16][64];
  int node0 = blockIdx.x * 64, n0 = blockIdx.y * 64;
  int tid = threadIdx.x, tx = tid & 15, ty = tid >> 4;
  float acc[4][4] = {};
  for (int k0 = 0; k0 < 512; k0 += 16){
    __syncthreads();
    {
      int m = tid >> 2, k4 = (tid & 3) * 4;
      float4 hv = *(const float4*)(hbuf + (size_t)(node0 + m) * 512 + k0 + k4);
      As[k4 + 0][m] = hv.x;
      As[k4 + 1][m] = hv.y;
      As[k4 + 2][m] = hv.z;
      As[k4 + 3][m] = hv.w;
      #pragma unroll
      for (int r = 0; r < 4; ++r){
        int e = tid + 256 * r;
        int k = e >> 6, n = e & 63;
        Bs[k][n] = W2[(size_t)(k0 + k) * 256 + n0 + n];
      }
    }
    __syncthreads();
    #pragma unroll
    for (int k = 0; k < 16; ++k){
      float4 a = *(const float4*)&As[k][ty * 4];
      float4 bq = *(const float4*)&Bs[k][tx * 4];
      acc[0][0]+=a.x*bq.x; acc[0][1]+=a.x*bq.y; acc[0][2]+=a.x*bq.z; acc[0][3]+=a.x*bq.w;
      acc[1][0]+=a.y*bq.x; acc[1][1]+=a.y*bq.y; acc[1][2]+=a.y*bq.z; acc[1][3]+=a.y*bq.w;
      acc[2][0]+=a.z*bq.x; acc[2][1]+=a.z*bq.y; acc[2][2]+=a.z*bq.z; acc[2][3]+=a.z*bq.w;
      acc[3][0]+=a.w*bq.x; acc[3][1]+=a.w*bq.y; acc[3][2]+=a.w*bq.z; acc[3][3]+=a.w*bq.w;
    }
  }
  float cs[4];
  #pragma unroll
  for (int c = 0; c < 4; ++c){
    float bb = b2[n0 + tx * 4 + c];
    cs[c] = (acc[0][c] + bb) + (acc[1][c] + bb) + (acc[2][c] + bb) + (acc[3][c] + bb);
  }
  __syncthreads();
  red[ty][tx*4+0] = cs[0]; red[ty][tx*4+1] = cs[1];
  red[ty][tx*4+2] = cs[2]; red[ty][tx*4+3] = cs[3];
  __syncthreads();
  if (tid < 64){
    float s = 0.f;
    #pragma unroll
    for (int t = 0; t < 16; ++t) s += red[t][tid];
    int node_g0 = base + node0;
    int g = node_g0 >> 10;
    int blk = (node_g0 >> 6) & 15;
    parts[(size_t)(g * 16 + blk) * 256 + n0 + tid] = s;
  }
}

// ---------------- final: per-graph mean, homophily, head MLP; OUT IS FLOAT32 -----
__global__ __launch_bounds__(256) void final_kernel(
    const float* __restrict__ parts, const unsigned* __restrict__ homoc,
    const float* __restrict__ mW1, const float* __restrict__ mb1,
    const float* __restrict__ mW2, const float* __restrict__ mb2,
    float* __restrict__ out){
  __shared__ float gv[261];
  __shared__ float z[256];
  int g = blockIdx.x, t = threadIdx.x;
  float s = 0.f;
  #pragma unroll
  for (int p = 0; p < 16; ++p) s += parts[(size_t)(g * 16 + p) * 256 + t];
  float dmean = s * (1.f / 1024.f);
  gv[t] = lrelu(dmean);
  if (t < 5) gv[256 + t] = lrelu((float)homoc[g * 5 + t] * (1.f / 97280.f));
  __syncthreads();
  float acc = mb1[t];
  for (int f = 0; f < 261; ++f) acc += gv[f] * mW1[(size_t)f * 256 + t];
  z[t] = lrelu(acc);
  __syncthreads();
  if (t < 3){
    float o = mb2[t];
    for (int f = 0; f < 256; ++f) o += z[f] * mW2[f * 3 + t];
    out[g * 3 + t] = o;
  }
}

// ---------------- diag: encode HARD failure info into out[0] ---------------------
__global__ __launch_bounds__(64) void diag_kernel(float* out, float hostcode){
  if (threadIdx.x == 0 && hostcode != 0.f) out[0] = hostcode;
}

extern "C" void kernel_launch(void* const* d_in, const int* in_sizes, int n_in,
                              void* d_out, int out_size, void* d_ws, size_t ws_size,
                              hipStream_t stream){
  (void)out_size;
  static const int E[20] = {65536,196608,65536,65536,640,64,4096,64,16384,128,8192,64,
                            100864,512,131072,256,66816,256,768,3};
  int map[20];
  float hostcode = 0.f;
  bool runnable = true;
  for (int i = 0; i < 20; ++i) map[i] = (i < n_in) ? i : 0;
  if (n_in < 19){
    hostcode = 4.0e7f; runnable = false;
  } else {
    bool ident = (n_in >= 20);
    if (ident) for (int i = 0; i < 20; ++i) if (in_sizes[i] != E[i]) { ident = false; break; }
    if (!ident){
      bool drop = true;
      for (int i = 0; i < 19 && drop; ++i){
        int ei = (i < 3) ? i : i + 1;
        if (in_sizes[i] != E[ei]) drop = false;
      }
      bool tail = false;
      if (!drop && n_in >= 20){
        tail = true;
        for (int i = 0; i < 19 && tail; ++i){
          int ei = (i < 3) ? i : i + 1;
          if (in_sizes[i] != E[ei]) tail = false;
        }
        if (tail && in_sizes[19] != E[3]) tail = false;
      }
      if (drop){
        for (int i = 0; i < 3; ++i) map[i] = i;
        map[3] = 0;
        for (int i = 4; i < 20; ++i) map[i] = i - 1;
      } else if (tail){
        for (int i = 0; i < 3; ++i) map[i] = i;
        map[3] = 19;
        for (int i = 4; i < 20; ++i) map[i] = i - 1;
      } else {
        int firstbad = 0;
        for (int i = 0; i < 20; ++i){
          if (i >= n_in || in_sizes[i] != E[i]) { firstbad = i; break; }
        }
        hostcode = 2.0e7f + 1.0e6f * (float)firstbad;
      }
    }
  }
  const float* x    = (const float*)d_in[map[0]];
  const float* pos  = (const float*)d_in[map[1]];
  const float* tq   = (const float*)d_in[map[2]];
  const float* c1W1 = (const float*)d_in[map[4]];
  const float* c1b1 = (const float*)d_in[map[5]];
  const float* c1W2 = (const float*)d_in[map[6]];
  const float* c1b2 = (const float*)d_in[map[7]];
  const float* c2W1 = (const float*)d_in[map[8]];
  const float* c2b1 = (const float*)d_in[map[9]];
  const float* c2W2 = (const float*)d_in[map[10]];
  const float* c2b2 = (const float*)d_in[map[11]];
  const float* l1W1 = (const float*)d_in[map[12]];
  const float* l1b1 = (const float*)d_in[map[13]];
  const float* l1W2 = (const float*)d_in[map[14]];
  const float* l1b2 = (const float*)d_in[map[15]];
  const float* mW1  = (const float*)d_in[map[16]];
  const float* mb1  = (const float*)d_in[map[17]];
  const float* mW2  = (const float*)d_in[map[18]];
  const float* mb2  = (const float*)d_in[map[19]];

  char* wsb = (char*)d_ws;
  size_t off = 0;
  auto alloc = [&](size_t bytes) -> char* {
    char* p = wsb + off;
    off += (bytes + 255) & ~(size_t)255;
    return p;
  };
  float* feat  = (float*)alloc((size_t)NT * 5 * 4);
  float* sqv   = (float*)alloc((size_t)NT * 4);
  float* xf1   = (float*)alloc((size_t)NT * 64 * 4);
  float* xf2   = (float*)alloc((size_t)NT * 64 * 4);
  float* xf3   = (float*)alloc((size_t)NT * 64 * 4);
  int*   idx15 = (int*)alloc((size_t)NT * 15 * 4);
  unsigned* homoc = (unsigned*)alloc(320 * 4);
  float* parts = (float*)alloc((size_t)NB * 16 * 256 * 4);

  size_t fixed_off = off;
  int C = 4;
  while (C < 64 && fixed_off + (size_t)(NT / C) * 2048 + 256 > ws_size) C <<= 1;
  int chunkN = NT / C;
  bool wsbad = fixed_off + (size_t)chunkN * 2048 + 256 > ws_size;
  float* R    = (float*)alloc((size_t)chunkN * 2048);
  float* U    = R;
  float* V64  = R + (size_t)chunkN * 64;
  float* V128 = R + (size_t)chunkN * 128;
  float* hbuf = R;
  if (wsbad && hostcode == 0.f) hostcode = 5.0e6f;

  int ftype = 0;
  (void)hipGetLastError();
  #define LCK(ty) do { if (hipGetLastError() != hipSuccess && ftype == 0) ftype = (ty); } while(0)

  dim3 blk(256);
  if (runnable){
    prep_kernel<<<dim3((NT + 255) / 256), blk, 0, stream>>>(x, pos, tq, feat, sqv, homoc);
    LCK(1);
    knn5f_kernel<<<dim3(NB * 256), blk, 0, stream>>>(feat, sqv, idx15, homoc);
    LCK(2);

    if (!wsbad){
      for (int c = 0; c < C; ++c){
        int base = c * chunkN;
        uv_kernel<5, 64, 1><<<dim3(chunkN / 32, 1), blk, 0, stream>>>(feat + (size_t)base * 5, c1W1, c1b1, U, V64);
        LCK(4);
        edge_kernel<64, true><<<dim3(chunkN / 4), blk, 0, stream>>>(U, V64, idx15, c1W2, c1b2, xf1, sqv, base);
        LCK(5);
      }
      knn64_kernel<<<dim3(NB * 256), blk, 0, stream>>>(xf1, sqv, idx15);
      LCK(7);
      for (int c = 0; c < C; ++c){
        int base = c * chunkN;
        uv_kernel<64, 128, 2><<<dim3(chunkN / 32, 2), blk, 0, stream>>>(xf1 + (size_t)base * 64, c2W1, c2b1, U, V128);
        LCK(8);
        edge_kernel<128, true><<<dim3(chunkN / 4), blk, 0, stream>>>(U, V128, idx15, c2W2, c2b2, xf2, sqv, base);
        LCK(9);
      }
      knn64_kernel<<<dim3(NB * 256), blk, 0, stream>>>(xf2, sqv, idx15);
      LCK(7);
      for (int c = 0; c < C; ++c){
        int base = c * chunkN;
        uv_kernel<64, 128, 2><<<dim3(chunkN / 32, 2), blk, 0, stream>>>(xf2 + (size_t)base * 64, c2W1, c2b1, U, V128);
        LCK(8);
        edge_kernel<128, false><<<dim3(chunkN / 4), blk, 0, stream>>>(U, V128, idx15, c2W2, c2b2, xf3, sqv, base);
        LCK(9);
      }
      for (int c = 0; c < C; ++c){
        int base = c * chunkN;
        gemm1_kernel<<<dim3(chunkN / 64, 8), blk, 0, stream>>>(feat, xf1, xf2, xf3, l1W1, l1b1, hbuf, base);
        LCK(10);
        gemm2_kernel<<<dim3(chunkN / 64, 4), blk, 0, stream>>>(hbuf, l1W2, l1b2, parts, base);
        LCK(11);
      }
    }
    final_kernel<<<dim3(NB), blk, 0, stream>>>(parts, homoc, mW1, mb1, mW2, mb2, (float*)d_out);
    LCK(12);
  }
  if (ftype != 0 && hostcode == 0.f) hostcode = 1.0e7f * (float)ftype;
  diag_kernel<<<dim3(1), dim3(64), 0, stream>>>((float*)d_out, hostcode);
  #undef LCK
}

// Round 11
// 3980.658 us; speedup vs baseline: 1.2839x; 1.0773x over previous
//
#include <hip/hip_runtime.h>

#define DEV __device__ __forceinline__

static constexpr int NB = 64;     // graphs
static constexpr int NN = 1024;   // nodes per graph
static constexpr int NT = NB * NN;

DEV float lrelu(float v){ return v >= 0.f ? v : 0.01f * v; }

// monotone map f32 -> u32 (ascending)
DEV unsigned keyf(float d){
  unsigned u = __float_as_uint(d);
  return (u & 0x80000000u) ? ~u : (u | 0x80000000u);
}

DEV void wave_lds_fence(){
  __builtin_amdgcn_wave_barrier();
  asm volatile("s_waitcnt lgkmcnt(0)" ::: "memory");
  __builtin_amdgcn_sched_barrier(0);
  __builtin_amdgcn_wave_barrier();
}

DEV unsigned wavesum_u(unsigned v){
  #pragma unroll
  for (int d = 1; d < 64; d <<= 1) v += (unsigned)__shfl_xor((int)v, d);
  return v;
}

// Select the k smallest of the wave's 1024 keys (16/lane; key = (dist u32, idx),
// idx = s*64+lane, ties on dist broken by lower idx == top_k semantics).
// Register-only bit-serial radix; no LDS. Returns 16-bit mask of selected keys.
DEV unsigned radix_sel(const unsigned* dk, int k, int lane){
  unsigned active = 0xFFFFu, sel = 0u;
  unsigned kk = (unsigned)k, ta = 1024u;
  // --- dist bits, MSB -> LSB, early-exit when resolved ---
  #pragma unroll 1
  for (int b = 31; b >= 0; --b){
    unsigned m1 = 0u;
    #pragma unroll
    for (int s = 0; s < 16; ++s) m1 |= ((dk[s] >> b) & 1u) << s;
    unsigned m0 = active & ~m1;
    unsigned c0 = wavesum_u((unsigned)__popc(m0));
    if (c0 >= kk){ active = m0; ta = c0; }
    else { sel |= m0; kk -= c0; active &= m1; ta -= c0; }
    if (ta == kk){ sel |= active; active = 0u; ta = 0u; }
    if (__builtin_amdgcn_readfirstlane(ta) == 0u) return sel;
  }
  // --- idx tie-break bits: c = s*64+lane; bits 9..6 from s, 5..0 from lane ---
  {
    const unsigned smask[4] = {0xFF00u, 0xF0F0u, 0xCCCCu, 0xAAAAu}; // s bit 3,2,1,0
    #pragma unroll
    for (int i = 0; i < 4; ++i){
      unsigned m1 = smask[i];
      unsigned m0 = active & ~m1;
      unsigned c0 = wavesum_u((unsigned)__popc(m0));
      if (c0 >= kk){ active = m0; ta = c0; }
      else { sel |= m0; kk -= c0; active &= m1; ta -= c0; }
      if (ta == kk){ sel |= active; active = 0u; ta = 0u; }
    }
    #pragma unroll
    for (int b = 5; b >= 0; --b){
      unsigned m1 = ((lane >> b) & 1) ? 0xFFFFu : 0u;
      unsigned m0 = active & ~m1;
      unsigned c0 = wavesum_u((unsigned)__popc(m0));
      if (c0 >= kk){ active = m0; ta = c0; }
      else { sel |= m0; kk -= c0; active &= m1; ta -= c0; }
      if (ta == kk){ sel |= active; active = 0u; ta = 0u; }
    }
  }
  return sel;
}

// ---------------- prep: feat = [tq, x, pos], sq(feat), zero ALL homo counts ------
__global__ __launch_bounds__(256) void prep_kernel(
    const float* __restrict__ x, const float* __restrict__ pos, const float* __restrict__ tq,
    float* __restrict__ feat, float* __restrict__ sqv, unsigned* __restrict__ homoc){
  int n = blockIdx.x * 256 + threadIdx.x;
  if (n < NT){
    float f0 = tq[n], f1 = x[n], f2 = pos[n*3+0], f3 = pos[n*3+1], f4 = pos[n*3+2];
    feat[n*5+0] = f0; feat[n*5+1] = f1; feat[n*5+2] = f2; feat[n*5+3] = f3; feat[n*5+4] = f4;
    sqv[n] = f0*f0 + f1*f1 + f2*f2 + f3*f3 + f4*f4;
  }
  if (blockIdx.x == 0){
    for (int e = threadIdx.x; e < 320; e += 256) homoc[e] = 0u;
  }
}

// ---------------- fused kNN on 5-dim feat: K=15 idx write + K=95 homophily -------
__global__ __launch_bounds__(256) void knn5f_kernel(
    const float* __restrict__ feat, const float* __restrict__ sqv,
    int* __restrict__ idx_out, unsigned* __restrict__ homoc){
  __shared__ float fs[NN * 5];
  __shared__ float ss[NN];
  __shared__ unsigned wctr[4];
  int b = blockIdx.x >> 8;
  int q0 = (blockIdx.x & 255) * 4;
  const float* fg = feat + (size_t)b * NN * 5;
  for (int e = threadIdx.x; e < NN * 5; e += 256) fs[e] = fg[e];
  const float* sg = sqv + (size_t)b * NN;
  for (int e = threadIdx.x; e < NN; e += 256) ss[e] = sg[e];
  __syncthreads();
  int w = threadIdx.x >> 6, lane = threadIdx.x & 63;
  int q = q0 + w;
  float qf[5];
  #pragma unroll
  for (int c = 0; c < 5; ++c) qf[c] = fs[q*5+c];
  float sqq = ss[q];
  unsigned dk[16];
  #pragma unroll
  for (int s = 0; s < 16; ++s){
    int c = s * 64 + lane;
    float dot = qf[0]*fs[c*5+0] + qf[1]*fs[c*5+1] + qf[2]*fs[c*5+2] + qf[3]*fs[c*5+3] + qf[4]*fs[c*5+4];
    float d = sqq + ss[c] - 2.f * dot;
    dk[s] = keyf(d);
  }
  // --- selection 1: K=15, self included (self dist exactly 0 -> always in) -----
  unsigned sel = radix_sel(dk, 15, lane);
  if (lane == 0) wctr[w] = 0u;
  wave_lds_fence();
  #pragma unroll
  for (int s = 0; s < 16; ++s){
    if ((sel >> s) & 1u){
      unsigned pos = atomicAdd(&wctr[w], 1u);
      idx_out[(size_t)(b*NN + q) * 15 + pos] = b*NN + s*64 + lane;
    }
  }
  // --- selection 2: K=95, self excluded; count homophily -----------------------
  int sq_s = q >> 6, sq_l = q & 63;
  #pragma unroll
  for (int s = 0; s < 16; ++s)
    if (s == sq_s && lane == sq_l) dk[s] = 0xFFFFFFFFu;
  unsigned sel2 = radix_sel(dk, 95, lane);
  unsigned cnt5[5] = {0,0,0,0,0};
  #pragma unroll
  for (int s = 0; s < 16; ++s){
    if ((sel2 >> s) & 1u){
      int c = s * 64 + lane;
      #pragma unroll
      for (int ch = 0; ch < 5; ++ch) cnt5[ch] += (fs[c*5+ch] == qf[ch]) ? 1u : 0u;
    }
  }
  #pragma unroll
  for (int ch = 0; ch < 5; ++ch){
    unsigned v = cnt5[ch];
    #pragma unroll
    for (int d = 32; d >= 1; d >>= 1) v += (unsigned)__shfl_xor((int)v, d);
    if (lane == 0) atomicAdd(&homoc[b*5+ch], v);
  }
}

// ---------------- kNN (k=15) on 64-dim, 128-candidate chunks + register radix ----
__global__ __launch_bounds__(256) void knn64_kernel(
    const float* __restrict__ X, const float* __restrict__ sqv, int* __restrict__ idx_out){
  __shared__ __align__(16) float chunk[128 * 64];  // swizzled
  __shared__ float sqc[128];
  __shared__ __align__(16) float qf[4][64];
  __shared__ unsigned wctr[4];
  int b = blockIdx.x >> 8;
  int q0 = (blockIdx.x & 255) * 4;
  int w = threadIdx.x >> 6, lane = threadIdx.x & 63;
  int q = q0 + w;
  int qg = b * NN + q;
  qf[w][lane] = X[(size_t)qg * 64 + lane];
  float sqq = sqv[qg];
  float dist[16];
  #pragma unroll 1
  for (int ch = 0; ch < 8; ++ch){
    __syncthreads();
    {
      const float* xg = X + (size_t)(b * NN + ch * 128) * 64;
      #pragma unroll
      for (int r = 0; r < 8; ++r){
        int e = threadIdx.x + 256 * r;       // e < 2048 : (c, f4)
        int c = e >> 4, f4 = e & 15;
        float4 v = *(const float4*)(xg + c * 64 + f4 * 4);
        *(float4*)&chunk[c * 64 + (((f4 ^ (c & 15))) << 2)] = v;
      }
      if (threadIdx.x < 128) sqc[threadIdx.x] = sqv[b * NN + ch * 128 + threadIdx.x];
    }
    __syncthreads();
    #pragma unroll
    for (int i = 0; i < 2; ++i){
      int cl = lane + 64 * i;
      float acc = 0.f;
      #pragma unroll
      for (int f4 = 0; f4 < 16; ++f4){
        float4 qv = *(const float4*)&qf[w][f4 * 4];
        float4 xv = *(const float4*)&chunk[cl * 64 + (((f4 ^ (cl & 15))) << 2)];
        acc += qv.x*xv.x + qv.y*xv.y + qv.z*xv.z + qv.w*xv.w;
      }
      dist[ch * 2 + i] = sqq + sqc[cl] - 2.f * acc;
    }
  }
  unsigned dk[16];
  #pragma unroll
  for (int s = 0; s < 16; ++s) dk[s] = keyf(dist[s]);   // cand idx = s*64+lane
  unsigned sel = radix_sel(dk, 15, lane);
  if (lane == 0) wctr[w] = 0u;
  wave_lds_fence();
  #pragma unroll
  for (int s = 0; s < 16; ++s){
    if ((sel >> s) & 1u){
      unsigned pos = atomicAdd(&wctr[w], 1u);
      idx_out[(size_t)qg * 15 + pos] = b * NN + s*64 + lane;
    }
  }
}

// ---------------- per-node U,V with output-column split (LDS <= 33KB) ------------
template<int F, int H1, int YS>
__global__ __launch_bounds__(256) void uv_kernel(
    const float* __restrict__ X, const float* __restrict__ W1, const float* __restrict__ b1,
    float* __restrict__ U, float* __restrict__ V){
  constexpr int HH = H1 / YS;
  __shared__ float w1s[2 * F * HH];
  constexpr int NPI = 256 / HH;
  __shared__ float xs[NPI][F];
  constexpr int NPB = 32;
  int node0 = blockIdx.x * NPB;
  int y0 = blockIdx.y * HH;
  for (int e = threadIdx.x; e < 2 * F * HH; e += 256)
    w1s[e] = W1[(size_t)(e / HH) * H1 + y0 + (e % HH)];
  int ol = threadIdx.x % HH, nn = threadIdx.x / HH;
  float b1o = b1[y0 + ol];
  for (int it = 0; it < NPB / NPI; ++it){
    __syncthreads();
    int nbase = node0 + it * NPI;
    for (int e = threadIdx.x; e < NPI * F; e += 256)
      xs[e / F][e % F] = X[(size_t)(nbase + e / F) * F + (e % F)];
    __syncthreads();
    float u = b1o, v = 0.f;
    #pragma unroll
    for (int f = 0; f < F; ++f){
      float xf = xs[nn][f];
      float wt = w1s[f * HH + ol], wb = w1s[(F + f) * HH + ol];
      u += xf * (wt - wb);
      v += xf * wb;
    }
    size_t node = nbase + nn;
    U[node * H1 + y0 + ol] = u;
    V[node * H1 + y0 + ol] = v;
  }
}

// ---------------- edge aggregation; optional fused sq-norm write -----------------
template<int H1, bool WRSQ>
__global__ __launch_bounds__(256) void edge_kernel(
    const float* __restrict__ U, const float* __restrict__ V,
    const int* __restrict__ idx15, const float* __restrict__ W2,
    const float* __restrict__ b2, float* __restrict__ out,
    float* __restrict__ sqv, int base){
  constexpr int H14 = H1 / 4;
  __shared__ __align__(16) float w2t[64 * H1];        // [o][h] xor-swizzled
  __shared__ __align__(16) float h1s[4][15 * H1];
  __shared__ int idxs[4][16];
  int w = threadIdx.x >> 6, lane = threadIdx.x & 63;
  int node_l = blockIdx.x * 4 + w;
  int node_g = base + node_l;
  for (int e = threadIdx.x; e < 64 * H14; e += 256){
    int o = e & 63, h4 = e >> 6;
    float vv[4];
    #pragma unroll
    for (int j = 0; j < 4; ++j) vv[j] = W2[(size_t)(h4 * 4 + j) * 64 + o];
    float* dst = &w2t[o * H1 + (((h4 ^ (o & 7))) << 2)];
    #pragma unroll
    for (int j = 0; j < 4; ++j) dst[j] = vv[j];
  }
  if (lane < 15) idxs[w][lane] = idx15[(size_t)node_g * 15 + lane] - base;
  __syncthreads();
  for (int e = lane; e < 15 * H14; e += 64){
    int j = e / H14, h4 = e % H14;
    int jn = idxs[w][j];
    float4 uu = *(const float4*)(U + (size_t)node_l * H1 + h4 * 4);
    float4 vv = *(const float4*)(V + (size_t)jn * H1 + h4 * 4);
    float4 h;
    h.x = lrelu(uu.x + vv.x); h.y = lrelu(uu.y + vv.y);
    h.z = lrelu(uu.z + vv.z); h.w = lrelu(uu.w + vv.w);
    *(float4*)&h1s[w][j * H1 + h4 * 4] = h;
  }
  __syncthreads();
  int o = lane;
  float acc[15];
  #pragma unroll
  for (int j = 0; j < 15; ++j) acc[j] = 0.f;
  for (int h4 = 0; h4 < H14; ++h4){
    float4 wv = *(const float4*)&w2t[o * H1 + (((h4 ^ (o & 7))) << 2)];
    #pragma unroll
    for (int j = 0; j < 15; ++j){
      float4 hv = *(const float4*)&h1s[w][j * H1 + h4 * 4];
      acc[j] += wv.x*hv.x + wv.y*hv.y + wv.z*hv.z + wv.w*hv.w;
    }
  }
  float b2o = b2[o];
  float s = 0.f;
  #pragma unroll
  for (int j = 0; j < 15; ++j) s += lrelu(acc[j] + b2o);
  out[(size_t)node_g * 64 + o] = s;
  if (WRSQ){
    float s2 = s * s;
    #pragma unroll
    for (int d = 1; d < 64; d <<= 1) s2 += __shfl_xor(s2, d);
    if (lane == 0) sqv[node_g] = s2;
  }
}

// ---------------- GEMM1: h = lrelu(cat @ l1_W1 + b1) -> fp32 chunk-local ---------
__global__ __launch_bounds__(256) void gemm1_kernel(
    const float* __restrict__ feat, const float* __restrict__ x1,
    const float* __restrict__ x2, const float* __restrict__ x3,
    const float* __restrict__ W1, const float* __restrict__ b1,
    float* __restrict__ hbuf, int base){
  __shared__ __align__(16) float As[16][64];
  __shared__ __align__(16) float Bs[16][64];
  int node0 = blockIdx.x * 64, n0 = blockIdx.y * 64;
  int tid = threadIdx.x, tx = tid & 15, ty = tid >> 4;
  float acc[4][4] = {};
  for (int k0 = 0; k0 < 197; k0 += 16){
    __syncthreads();
    #pragma unroll
    for (int r = 0; r < 4; ++r){
      int e = tid + 256 * r;
      int k = e >> 6, m = e & 63;
      int kk = k0 + k;
      size_t node = (size_t)base + node0 + m;
      float v;
      if (kk < 5) v = feat[node * 5 + kk];
      else if (kk < 69)  v = x1[node * 64 + kk - 5];
      else if (kk < 133) v = x2[node * 64 + kk - 69];
      else if (kk < 197) v = x3[node * 64 + kk - 133];
      else v = 0.f;
      As[k][m] = v;
      Bs[k][m] = (kk < 197) ? W1[(size_t)kk * 512 + n0 + m] : 0.f;
    }
    __syncthreads();
    #pragma unroll
    for (int k = 0; k < 16; ++k){
      float4 a = *(const float4*)&As[k][ty * 4];
      float4 bq = *(const float4*)&Bs[k][tx * 4];
      acc[0][0]+=a.x*bq.x; acc[0][1]+=a.x*bq.y; acc[0][2]+=a.x*bq.z; acc[0][3]+=a.x*bq.w;
      acc[1][0]+=a.y*bq.x; acc[1][1]+=a.y*bq.y; acc[1][2]+=a.y*bq.z; acc[1][3]+=a.y*bq.w;
      acc[2][0]+=a.z*bq.x; acc[2][1]+=a.z*bq.y; acc[2][2]+=a.z*bq.z; acc[2][3]+=a.z*bq.w;
      acc[3][0]+=a.w*bq.x; acc[3][1]+=a.w*bq.y; acc[3][2]+=a.w*bq.z; acc[3][3]+=a.w*bq.w;
    }
  }
  #pragma unroll
  for (int i = 0; i < 4; ++i){
    size_t node = node0 + ty * 4 + i;
    float4 st;
    st.x = lrelu(acc[i][0] + b1[n0 + tx*4 + 0]);
    st.y = lrelu(acc[i][1] + b1[n0 + tx*4 + 1]);
    st.z = lrelu(acc[i][2] + b1[n0 + tx*4 + 2]);
    st.w = lrelu(acc[i][3] + b1[n0 + tx*4 + 3]);
    *(float4*)(hbuf + node * 512 + n0 + tx * 4) = st;
  }
}

// ---------------- GEMM2: out = h @ l1_W2 + b2, fused per-graph partial col-sum ---
__global__ __launch_bounds__(256) void gemm2_kernel(
    const float* __restrict__ hbuf, const float* __restrict__ W2,
    const float* __restrict__ b2, float* __restrict__ parts, int base){
  __shared__ __align__(16) float As[16][64];
  __shared__ __align__(16) float Bs[16][64];
  __shared__ float red[16][64];
  int node0 = blockIdx.x * 64, n0 = blockIdx.y * 64;
  int tid = threadIdx.x, tx = tid & 15, ty = tid >> 4;
  float acc[4][4] = {};
  for (int k0 = 0; k0 < 512; k0 += 16){
    __syncthreads();
    {
      int m = tid >> 2, k4 = (tid & 3) * 4;
      float4 hv = *(const float4*)(hbuf + (size_t)(node0 + m) * 512 + k0 + k4);
      As[k4 + 0][m] = hv.x;
      As[k4 + 1][m] = hv.y;
      As[k4 + 2][m] = hv.z;
      As[k4 + 3][m] = hv.w;
      #pragma unroll
      for (int r = 0; r < 4; ++r){
        int e = tid + 256 * r;
        int k = e >> 6, n = e & 63;
        Bs[k][n] = W2[(size_t)(k0 + k) * 256 + n0 + n];
      }
    }
    __syncthreads();
    #pragma unroll
    for (int k = 0; k < 16; ++k){
      float4 a = *(const float4*)&As[k][ty * 4];
      float4 bq = *(const float4*)&Bs[k][tx * 4];
      acc[0][0]+=a.x*bq.x; acc[0][1]+=a.x*bq.y; acc[0][2]+=a.x*bq.z; acc[0][3]+=a.x*bq.w;
      acc[1][0]+=a.y*bq.x; acc[1][1]+=a.y*bq.y; acc[1][2]+=a.y*bq.z; acc[1][3]+=a.y*bq.w;
      acc[2][0]+=a.z*bq.x; acc[2][1]+=a.z*bq.y; acc[2][2]+=a.z*bq.z; acc[2][3]+=a.z*bq.w;
      acc[3][0]+=a.w*bq.x; acc[3][1]+=a.w*bq.y; acc[3][2]+=a.w*bq.z; acc[3][3]+=a.w*bq.w;
    }
  }
  float cs[4];
  #pragma unroll
  for (int c = 0; c < 4; ++c){
    float bb = b2[n0 + tx * 4 + c];
    cs[c] = (acc[0][c] + bb) + (acc[1][c] + bb) + (acc[2][c] + bb) + (acc[3][c] + bb);
  }
  __syncthreads();
  red[ty][tx*4+0] = cs[0]; red[ty][tx*4+1] = cs[1];
  red[ty][tx*4+2] = cs[2]; red[ty][tx*4+3] = cs[3];
  __syncthreads();
  if (tid < 64){
    float s = 0.f;
    #pragma unroll
    for (int t = 0; t < 16; ++t) s += red[t][tid];
    int node_g0 = base + node0;
    int g = node_g0 >> 10;
    int blk = (node_g0 >> 6) & 15;
    parts[(size_t)(g * 16 + blk) * 256 + n0 + tid] = s;
  }
}

// ---------------- final: per-graph mean, homophily, head MLP; OUT IS FLOAT32 -----
__global__ __launch_bounds__(256) void final_kernel(
    const float* __restrict__ parts, const unsigned* __restrict__ homoc,
    const float* __restrict__ mW1, const float* __restrict__ mb1,
    const float* __restrict__ mW2, const float* __restrict__ mb2,
    float* __restrict__ out){
  __shared__ float gv[261];
  __shared__ float z[256];
  int g = blockIdx.x, t = threadIdx.x;
  float s = 0.f;
  #pragma unroll
  for (int p = 0; p < 16; ++p) s += parts[(size_t)(g * 16 + p) * 256 + t];
  float dmean = s * (1.f / 1024.f);
  gv[t] = lrelu(dmean);
  if (t < 5) gv[256 + t] = lrelu((float)homoc[g * 5 + t] * (1.f / 97280.f));
  __syncthreads();
  float acc = mb1[t];
  for (int f = 0; f < 261; ++f) acc += gv[f] * mW1[(size_t)f * 256 + t];
  z[t] = lrelu(acc);
  __syncthreads();
  if (t < 3){
    float o = mb2[t];
    for (int f = 0; f < 256; ++f) o += z[f] * mW2[f * 3 + t];
    out[g * 3 + t] = o;
  }
}

// ---------------- diag: encode HARD failure info into out[0] ---------------------
__global__ __launch_bounds__(64) void diag_kernel(float* out, float hostcode){
  if (threadIdx.x == 0 && hostcode != 0.f) out[0] = hostcode;
}

extern "C" void kernel_launch(void* const* d_in, const int* in_sizes, int n_in,
                              void* d_out, int out_size, void* d_ws, size_t ws_size,
                              hipStream_t stream){
  (void)out_size;
  static const int E[20] = {65536,196608,65536,65536,640,64,4096,64,16384,128,8192,64,
                            100864,512,131072,256,66816,256,768,3};
  int map[20];
  float hostcode = 0.f;
  bool runnable = true;
  for (int i = 0; i < 20; ++i) map[i] = (i < n_in) ? i : 0;
  if (n_in < 19){
    hostcode = 4.0e7f; runnable = false;
  } else {
    bool ident = (n_in >= 20);
    if (ident) for (int i = 0; i < 20; ++i) if (in_sizes[i] != E[i]) { ident = false; break; }
    if (!ident){
      bool drop = true;
      for (int i = 0; i < 19 && drop; ++i){
        int ei = (i < 3) ? i : i + 1;
        if (in_sizes[i] != E[ei]) drop = false;
      }
      bool tail = false;
      if (!drop && n_in >= 20){
        tail = true;
        for (int i = 0; i < 19 && tail; ++i){
          int ei = (i < 3) ? i : i + 1;
          if (in_sizes[i] != E[ei]) tail = false;
        }
        if (tail && in_sizes[19] != E[3]) tail = false;
      }
      if (drop){
        for (int i = 0; i < 3; ++i) map[i] = i;
        map[3] = 0;
        for (int i = 4; i < 20; ++i) map[i] = i - 1;
      } else if (tail){
        for (int i = 0; i < 3; ++i) map[i] = i;
        map[3] = 19;
        for (int i = 4; i < 20; ++i) map[i] = i - 1;
      } else {
        int firstbad = 0;
        for (int i = 0; i < 20; ++i){
          if (i >= n_in || in_sizes[i] != E[i]) { firstbad = i; break; }
        }
        hostcode = 2.0e7f + 1.0e6f * (float)firstbad;
      }
    }
  }
  const float* x    = (const float*)d_in[map[0]];
  const float* pos  = (const float*)d_in[map[1]];
  const float* tq   = (const float*)d_in[map[2]];
  const float* c1W1 = (const float*)d_in[map[4]];
  const float* c1b1 = (const float*)d_in[map[5]];
  const float* c1W2 = (const float*)d_in[map[6]];
  const float* c1b2 = (const float*)d_in[map[7]];
  const float* c2W1 = (const float*)d_in[map[8]];
  const float* c2b1 = (const float*)d_in[map[9]];
  const float* c2W2 = (const float*)d_in[map[10]];
  const float* c2b2 = (const float*)d_in[map[11]];
  const float* l1W1 = (const float*)d_in[map[12]];
  const float* l1b1 = (const float*)d_in[map[13]];
  const float* l1W2 = (const float*)d_in[map[14]];
  const float* l1b2 = (const float*)d_in[map[15]];
  const float* mW1  = (const float*)d_in[map[16]];
  const float* mb1  = (const float*)d_in[map[17]];
  const float* mW2  = (const float*)d_in[map[18]];
  const float* mb2  = (const float*)d_in[map[19]];

  char* wsb = (char*)d_ws;
  size_t off = 0;
  auto alloc = [&](size_t bytes) -> char* {
    char* p = wsb + off;
    off += (bytes + 255) & ~(size_t)255;
    return p;
  };
  float* feat  = (float*)alloc((size_t)NT * 5 * 4);
  float* sqv   = (float*)alloc((size_t)NT * 4);
  float* xf1   = (float*)alloc((size_t)NT * 64 * 4);
  float* xf2   = (float*)alloc((size_t)NT * 64 * 4);
  float* xf3   = (float*)alloc((size_t)NT * 64 * 4);
  int*   idx15 = (int*)alloc((size_t)NT * 15 * 4);
  unsigned* homoc = (unsigned*)alloc(320 * 4);
  float* parts = (float*)alloc((size_t)NB * 16 * 256 * 4);

  size_t fixed_off = off;
  int C = 4;
  while (C < 64 && fixed_off + (size_t)(NT / C) * 2048 + 256 > ws_size) C <<= 1;
  int chunkN = NT / C;
  bool wsbad = fixed_off + (size_t)chunkN * 2048 + 256 > ws_size;
  float* R    = (float*)alloc((size_t)chunkN * 2048);
  float* U    = R;
  float* V64  = R + (size_t)chunkN * 64;
  float* V128 = R + (size_t)chunkN * 128;
  float* hbuf = R;
  if (wsbad && hostcode == 0.f) hostcode = 5.0e6f;

  int ftype = 0;
  (void)hipGetLastError();
  #define LCK(ty) do { if (hipGetLastError() != hipSuccess && ftype == 0) ftype = (ty); } while(0)

  dim3 blk(256);
  if (runnable){
    prep_kernel<<<dim3((NT + 255) / 256), blk, 0, stream>>>(x, pos, tq, feat, sqv, homoc);
    LCK(1);
    knn5f_kernel<<<dim3(NB * 256), blk, 0, stream>>>(feat, sqv, idx15, homoc);
    LCK(2);

    if (!wsbad){
      for (int c = 0; c < C; ++c){
        int base = c * chunkN;
        uv_kernel<5, 64, 1><<<dim3(chunkN / 32, 1), blk, 0, stream>>>(feat + (size_t)base * 5, c1W1, c1b1, U, V64);
        LCK(4);
        edge_kernel<64, true><<<dim3(chunkN / 4), blk, 0, stream>>>(U, V64, idx15, c1W2, c1b2, xf1, sqv, base);
        LCK(5);
      }
      knn64_kernel<<<dim3(NB * 256), blk, 0, stream>>>(xf1, sqv, idx15);
      LCK(7);
      for (int c = 0; c < C; ++c){
        int base = c * chunkN;
        uv_kernel<64, 128, 2><<<dim3(chunkN / 32, 2), blk, 0, stream>>>(xf1 + (size_t)base * 64, c2W1, c2b1, U, V128);
        LCK(8);
        edge_kernel<128, true><<<dim3(chunkN / 4), blk, 0, stream>>>(U, V128, idx15, c2W2, c2b2, xf2, sqv, base);
        LCK(9);
      }
      knn64_kernel<<<dim3(NB * 256), blk, 0, stream>>>(xf2, sqv, idx15);
      LCK(7);
      for (int c = 0; c < C; ++c){
        int base = c * chunkN;
        uv_kernel<64, 128, 2><<<dim3(chunkN / 32, 2), blk, 0, stream>>>(xf2 + (size_t)base * 64, c2W1, c2b1, U, V128);
        LCK(8);
        edge_kernel<128, false><<<dim3(chunkN / 4), blk, 0, stream>>>(U, V128, idx15, c2W2, c2b2, xf3, sqv, base);
        LCK(9);
      }
      for (int c = 0; c < C; ++c){
        int base = c * chunkN;
        gemm1_kernel<<<dim3(chunkN / 64, 8), blk, 0, stream>>>(feat, xf1, xf2, xf3, l1W1, l1b1, hbuf, base);
        LCK(10);
        gemm2_kernel<<<dim3(chunkN / 64, 4), blk, 0, stream>>>(hbuf, l1W2, l1b2, parts, base);
        LCK(11);
      }
    }
    final_kernel<<<dim3(NB), blk, 0, stream>>>(parts, homoc, mW1, mb1, mW2, mb2, (float*)d_out);
    LCK(12);
  }
  if (ftype != 0 && hostcode == 0.f) hostcode = 1.0e7f * (float)ftype;
  diag_kernel<<<dim3(1), dim3(64), 0, stream>>>((float*)d_out, hostcode);
  #undef LCK
}